// Round 2
// baseline (268.657 us; speedup 1.0000x reference)
//
#include <hip/hip_runtime.h>

#define T_DIM 8192
#define IN_DIM 4096
#define OUT_DIM 4096
#define R_DIM 64

typedef int i32x4 __attribute__((ext_vector_type(4)));
typedef float f32x4 __attribute__((ext_vector_type(4)));
typedef _Float16 f16x8 __attribute__((ext_vector_type(8)));

__device__ __forceinline__ int pack4(int4 v) {
  return (v.x & 255) | ((v.y & 255) << 8) | ((v.z & 255) << 16) | ((unsigned)v.w << 24);
}

// global -> LDS direct DMA, 16B per lane. AS casts go through integers:
// generic->AS1 is a plain 64-bit reinterpret; generic->AS3 truncates to the
// low 32 bits (shared aperture is 4GB-aligned, low 32 = LDS offset), which is
// exactly what clang's addrspacecast lowers to.
__device__ __forceinline__ void gload16(const void* g, void* l) {
  __builtin_amdgcn_global_load_lds(
      (const __attribute__((address_space(1))) void*)(unsigned long long)g,
      (__attribute__((address_space(3))) void*)(unsigned)(unsigned long long)l,
      16, 0, 0);
}

// int32 (values in [-8,7]) -> int8, 16 elements per thread-iteration
__global__ void cvt_i8_kernel(const int4* __restrict__ src, int4* __restrict__ dst, int n16) {
  int idx = blockIdx.x * blockDim.x + threadIdx.x;
  int stride = gridDim.x * blockDim.x;
  for (int i = idx; i < n16; i += stride) {
    int4 a = src[4 * i + 0], b = src[4 * i + 1], c = src[4 * i + 2], d = src[4 * i + 3];
    int4 r;
    r.x = pack4(a); r.y = pack4(b); r.z = pack4(c); r.w = pack4(d);
    dst[i] = r;
  }
}

// SRC==0: int8 operands from workspace via global_load_lds
// SRC==1: int32 operands direct, packed in-register (fallback if ws too small)
template <int SRC>
__global__ __launch_bounds__(256)
void w4a4_gemm(const char* __restrict__ A8, const char* __restrict__ B8,
               const int* __restrict__ A32, const int* __restrict__ B32,
               const float* __restrict__ sx, const float* __restrict__ sw,
               const float* __restrict__ ox, const float* __restrict__ ow,
               const float* __restrict__ bias, float* __restrict__ out) {
  __shared__ __align__(16) unsigned char smem[32768];
  char* sA = (char*)smem;          // [128][64] int8
  char* sB = (char*)smem + 8192;   // [128][64] int8

  const int bid = blockIdx.x;
  const int swz = (bid & 7) * 256 + (bid >> 3);   // XCD-aware, bijective (2048 % 8 == 0)
  const int tm = swz >> 5, tn = swz & 31;
  const int brow = tm * 128, bcol = tn * 128;

  const int t = threadIdx.x;
  const int w = t >> 6, l = t & 63;
  const int wr = w >> 1, wc = w & 1;        // 2x2 wave grid, 64x64 per wave
  const int l16 = l & 15, lk = l >> 4;

  const i32x4 zero4 = {0, 0, 0, 0};
  i32x4 iacc[4][4];
#pragma unroll
  for (int m = 0; m < 4; ++m)
#pragma unroll
    for (int n = 0; n < 4; ++n) iacc[m][n] = zero4;

  // staging geometry: tile = 512 x 16B chunks; thread t handles chunks t and t+256
  const int ar = t >> 2;          // tile row of chunk0
  const int ac = (t & 3) << 4;    // col offset (bytes for i8 / elements for i32)

  const char *gA0 = nullptr, *gA1 = nullptr, *gB0 = nullptr, *gB1 = nullptr;
  const int *hA0 = nullptr, *hA1 = nullptr, *hB0 = nullptr, *hB1 = nullptr;
  if constexpr (SRC == 0) {
    gA0 = A8 + (size_t)(brow + ar) * IN_DIM + ac;
    gA1 = gA0 + (size_t)64 * IN_DIM;
    gB0 = B8 + (size_t)(bcol + ar) * IN_DIM + ac;
    gB1 = gB0 + (size_t)64 * IN_DIM;
  } else {
    hA0 = A32 + (size_t)(brow + ar) * IN_DIM + ac;
    hA1 = hA0 + (size_t)64 * IN_DIM;
    hB0 = B32 + (size_t)(bcol + ar) * IN_DIM + ac;
    hB1 = hB0 + (size_t)64 * IN_DIM;
  }

  const char* fragA = sA + (size_t)(wr * 64 + l16) * 64 + lk * 16;
  const char* fragB = sB + (size_t)(wc * 64 + l16) * 64 + lk * 16;

  for (int k0 = 0; k0 < IN_DIM; k0 += 64) {
    if constexpr (SRC == 0) {
      gload16(gA0 + k0, sA + (w << 10));
      gload16(gA1 + k0, sA + 4096 + (w << 10));
      gload16(gB0 + k0, sB + (w << 10));
      gload16(gB1 + k0, sB + 4096 + (w << 10));
    } else {
      const int4* pA0 = (const int4*)(hA0 + k0);
      int4 r0 = {pack4(pA0[0]), pack4(pA0[1]), pack4(pA0[2]), pack4(pA0[3])};
      *(int4*)(sA + t * 16) = r0;
      const int4* pA1 = (const int4*)(hA1 + k0);
      int4 r1 = {pack4(pA1[0]), pack4(pA1[1]), pack4(pA1[2]), pack4(pA1[3])};
      *(int4*)(sA + 4096 + t * 16) = r1;
      const int4* pB0 = (const int4*)(hB0 + k0);
      int4 r2 = {pack4(pB0[0]), pack4(pB0[1]), pack4(pB0[2]), pack4(pB0[3])};
      *(int4*)(sB + t * 16) = r2;
      const int4* pB1 = (const int4*)(hB1 + k0);
      int4 r3 = {pack4(pB1[0]), pack4(pB1[1]), pack4(pB1[2]), pack4(pB1[3])};
      *(int4*)(sB + 4096 + t * 16) = r3;
    }
    __syncthreads();
    i32x4 av[4], bv[4];
#pragma unroll
    for (int m = 0; m < 4; ++m) av[m] = *(const i32x4*)(fragA + m * 1024);
#pragma unroll
    for (int n = 0; n < 4; ++n) bv[n] = *(const i32x4*)(fragB + n * 1024);
#pragma unroll
    for (int m = 0; m < 4; ++m)
#pragma unroll
      for (int n = 0; n < 4; ++n)
        iacc[m][n] = __builtin_amdgcn_mfma_i32_16x16x64_i8(av[m], bv[n], iacc[m][n], 0, 0, 0);
    __syncthreads();
  }

  // ---- epilogue: dequant scales into fp32 accumulator ----
  const int orow = brow + wr * 64 + lk * 4;   // + m*16 + r
  const int ocol = bcol + wc * 64 + l16;      // + n*16
  float swv[4], bvv[4];
#pragma unroll
  for (int n = 0; n < 4; ++n) { swv[n] = sw[ocol + n * 16]; bvv[n] = bias[ocol + n * 16]; }

  f32x4 facc[4][4];
#pragma unroll
  for (int m = 0; m < 4; ++m) {
#pragma unroll
    for (int r = 0; r < 4; ++r) {
      float sxv = sx[orow + m * 16 + r];
#pragma unroll
      for (int n = 0; n < 4; ++n) facc[m][n][r] = (float)iacc[m][n][r] * sxv * swv[n];
    }
  }

  // ---- outlier low-rank addmm via f16 MFMA (K=64 = 2 steps of K=32) ----
  // stage ox/ow tiles as f16 [128][64] (16KB each)
  _Float16* oA = (_Float16*)smem;
  _Float16* oB = (_Float16*)(smem + 16384);
#pragma unroll
  for (int j = 0; j < 4; ++j) {
    int c = j * 256 + t;            // 1024 chunks of 16B per tile
    int rr2 = c >> 3, c8 = (c & 7) << 3;
    const float* gp = ox + (size_t)(brow + rr2) * R_DIM + c8;
    float4 f0 = *(const float4*)gp;
    float4 f1 = *(const float4*)(gp + 4);
    f16x8 h;
    h[0] = (_Float16)f0.x; h[1] = (_Float16)f0.y; h[2] = (_Float16)f0.z; h[3] = (_Float16)f0.w;
    h[4] = (_Float16)f1.x; h[5] = (_Float16)f1.y; h[6] = (_Float16)f1.z; h[7] = (_Float16)f1.w;
    *(f16x8*)((char*)oA + (size_t)c * 16) = h;
    const float* gq = ow + (size_t)(bcol + rr2) * R_DIM + c8;
    f0 = *(const float4*)gq; f1 = *(const float4*)(gq + 4);
    f16x8 g;
    g[0] = (_Float16)f0.x; g[1] = (_Float16)f0.y; g[2] = (_Float16)f0.z; g[3] = (_Float16)f0.w;
    g[4] = (_Float16)f1.x; g[5] = (_Float16)f1.y; g[6] = (_Float16)f1.z; g[7] = (_Float16)f1.w;
    *(f16x8*)((char*)oB + (size_t)c * 16) = g;
  }
  __syncthreads();

  const char* qa = (const char*)oA + (size_t)(wr * 64 + l16) * 128 + lk * 16;
  const char* qb = (const char*)oB + (size_t)(wc * 64 + l16) * 128 + lk * 16;
#pragma unroll
  for (int s = 0; s < 2; ++s) {
    f16x8 ha[4], hb[4];
#pragma unroll
    for (int m = 0; m < 4; ++m) ha[m] = *(const f16x8*)(qa + m * 2048 + s * 64);
#pragma unroll
    for (int n = 0; n < 4; ++n) hb[n] = *(const f16x8*)(qb + n * 2048 + s * 64);
#pragma unroll
    for (int m = 0; m < 4; ++m)
#pragma unroll
      for (int n = 0; n < 4; ++n)
        facc[m][n] = __builtin_amdgcn_mfma_f32_16x16x32_f16(ha[m], hb[n], facc[m][n], 0, 0, 0);
  }

  // ---- store out = facc + bias ----
#pragma unroll
  for (int m = 0; m < 4; ++m)
#pragma unroll
    for (int r = 0; r < 4; ++r) {
      float* po = out + (size_t)(orow + m * 16 + r) * OUT_DIM + ocol;
#pragma unroll
      for (int n = 0; n < 4; ++n) po[n * 16] = facc[m][n][r] + bvv[n];
    }
}

extern "C" void kernel_launch(void* const* d_in, const int* in_sizes, int n_in,
                              void* d_out, int out_size, void* d_ws, size_t ws_size,
                              hipStream_t stream) {
  const int*   qx   = (const int*)d_in[0];
  const int*   wq   = (const int*)d_in[1];
  const float* sx   = (const float*)d_in[2];
  const float* sw   = (const float*)d_in[3];
  const float* ox   = (const float*)d_in[4];
  const float* ow   = (const float*)d_in[5];
  const float* bias = (const float*)d_in[6];
  float* out = (float*)d_out;

  const size_t needA = (size_t)T_DIM * IN_DIM;     // 32 MB
  const size_t needB = (size_t)OUT_DIM * IN_DIM;   // 16 MB

  if (ws_size >= needA + needB) {
    char* a8 = (char*)d_ws;
    char* b8 = a8 + needA;
    cvt_i8_kernel<<<1024, 256, 0, stream>>>((const int4*)qx, (int4*)a8, (int)(needA / 16));
    cvt_i8_kernel<<<1024, 256, 0, stream>>>((const int4*)wq, (int4*)b8, (int)(needB / 16));
    w4a4_gemm<0><<<2048, 256, 0, stream>>>(a8, b8, nullptr, nullptr, sx, sw, ox, ow, bias, out);
  } else {
    w4a4_gemm<1><<<2048, 256, 0, stream>>>(nullptr, nullptr, qx, wq, sx, sw, ox, ow, bias, out);
  }
}

// Round 3
// 193.413 us; speedup vs baseline: 1.3890x; 1.3890x over previous
//
#include <hip/hip_runtime.h>

#define T_DIM 8192
#define IN_DIM 4096
#define OUT_DIM 4096
#define R_DIM 64
#define NKT 64   // K-tiles of 64 int8 elements

typedef int i32x4 __attribute__((ext_vector_type(4)));
typedef float f32x4 __attribute__((ext_vector_type(4)));
typedef _Float16 f16x8 __attribute__((ext_vector_type(8)));

__device__ __forceinline__ int pack4(int4 v) {
  return (v.x & 255) | ((v.y & 255) << 8) | ((v.z & 255) << 16) | ((unsigned)v.w << 24);
}

// global -> LDS direct DMA, 16B per lane (wave-uniform LDS base + lane*16).
__device__ __forceinline__ void gload16(const void* g, void* l) {
  __builtin_amdgcn_global_load_lds(
      (const __attribute__((address_space(1))) void*)(unsigned long long)g,
      (__attribute__((address_space(3))) void*)(unsigned)(unsigned long long)l,
      16, 0, 0);
}

__global__ void cvt_i8_kernel(const int4* __restrict__ src, int4* __restrict__ dst, int n16) {
  int idx = blockIdx.x * blockDim.x + threadIdx.x;
  int stride = gridDim.x * blockDim.x;
  for (int i = idx; i < n16; i += stride) {
    int4 a = src[4 * i + 0], b = src[4 * i + 1], c = src[4 * i + 2], d = src[4 * i + 3];
    int4 r;
    r.x = pack4(a); r.y = pack4(b); r.z = pack4(c); r.w = pack4(d);
    dst[i] = r;
  }
}

// ---------------- 256x256 deep-pipelined i8 GEMM ----------------
// 512 threads = 8 waves (2M x 4N), per-wave output 128x64.
// LDS: 4 buffers x (A 16KB + B 16KB) = 128KB. Counted vmcnt(8), depth-3 prefetch.
__global__ __launch_bounds__(512, 2)
void w4a4_gemm256(const char* __restrict__ A8, const char* __restrict__ B8,
                  const float* __restrict__ sx, const float* __restrict__ sw,
                  const float* __restrict__ ox, const float* __restrict__ ow,
                  const float* __restrict__ bias, float* __restrict__ out) {
  __shared__ __align__(16) char smem[131072];

  const int bid = blockIdx.x;
  const int swz = (bid & 7) * 64 + (bid >> 3);   // bijective XCD swizzle (512%8==0)
  const int tm = swz >> 4, tn = swz & 15;        // 32 x 16 tile grid
  const int brow = tm * 256, bcol = tn * 256;

  const int t = threadIdx.x;
  const int w = t >> 6, l = t & 63;
  const int wr = w >> 2, wc = w & 3;             // 2 x 4 wave grid
  const int l16 = l & 15, lk = l >> 4;

  // ---- staging source (pre-swizzled global chunk: c ^= (row>>1)&3) ----
  const int srow = w * 16 + (l >> 2);                       // 0..127 within half
  const int scol = ((l & 3) ^ ((l >> 3) & 3)) << 4;
  const char* aS0 = A8 + (size_t)(brow + srow) * IN_DIM + scol;
  const char* aS1 = aS0 + (size_t)128 * IN_DIM;
  const char* bS0 = B8 + (size_t)(bcol + srow) * IN_DIM + scol;
  const char* bS1 = bS0 + (size_t)128 * IN_DIM;
  char* const stDst = smem + w * 1024;   // + buf*32768 + {0,8192,16384,24576}

  // ---- fragment read offsets (same XOR involution on read) ----
  const int xorc = (lk ^ ((l16 >> 1) & 3)) << 4;
  const char* aR = smem + (wr * 128 + l16) * 64 + xorc;          // + buf*32768 + m*1024
  const char* bR = smem + 16384 + (wc * 64 + l16) * 64 + xorc;   // + buf*32768 + n*1024

  i32x4 acc[8][4];
#pragma unroll
  for (int m = 0; m < 8; ++m)
#pragma unroll
    for (int n = 0; n < 4; ++n) acc[m][n] = (i32x4){0, 0, 0, 0};

  auto stage = [&](int kt) {
    const int k0 = kt << 6;
    char* d = stDst + ((kt & 3) << 15);
    gload16(aS0 + k0, d);
    gload16(aS1 + k0, d + 8192);
    gload16(bS0 + k0, d + 16384);
    gload16(bS1 + k0, d + 24576);
  };

  auto compute = [&](int kt) {
    const int bo = (kt & 3) << 15;
    const char* sa = aR + bo;
    const char* sb = bR + bo;
    i32x4 b0 = *(const i32x4*)(sb);
    i32x4 b1 = *(const i32x4*)(sb + 1024);
    i32x4 b2 = *(const i32x4*)(sb + 2048);
    i32x4 b3 = *(const i32x4*)(sb + 3072);
#pragma unroll
    for (int mh = 0; mh < 4; ++mh) {
      i32x4 a0 = *(const i32x4*)(sa + mh * 2048);
      i32x4 a1 = *(const i32x4*)(sa + mh * 2048 + 1024);
      __builtin_amdgcn_s_setprio(1);
      acc[2 * mh][0] = __builtin_amdgcn_mfma_i32_16x16x64_i8(a0, b0, acc[2 * mh][0], 0, 0, 0);
      acc[2 * mh][1] = __builtin_amdgcn_mfma_i32_16x16x64_i8(a0, b1, acc[2 * mh][1], 0, 0, 0);
      acc[2 * mh][2] = __builtin_amdgcn_mfma_i32_16x16x64_i8(a0, b2, acc[2 * mh][2], 0, 0, 0);
      acc[2 * mh][3] = __builtin_amdgcn_mfma_i32_16x16x64_i8(a0, b3, acc[2 * mh][3], 0, 0, 0);
      acc[2 * mh + 1][0] = __builtin_amdgcn_mfma_i32_16x16x64_i8(a1, b0, acc[2 * mh + 1][0], 0, 0, 0);
      acc[2 * mh + 1][1] = __builtin_amdgcn_mfma_i32_16x16x64_i8(a1, b1, acc[2 * mh + 1][1], 0, 0, 0);
      acc[2 * mh + 1][2] = __builtin_amdgcn_mfma_i32_16x16x64_i8(a1, b2, acc[2 * mh + 1][2], 0, 0, 0);
      acc[2 * mh + 1][3] = __builtin_amdgcn_mfma_i32_16x16x64_i8(a1, b3, acc[2 * mh + 1][3], 0, 0, 0);
      __builtin_amdgcn_s_setprio(0);
    }
  };

  // prologue: 3 tiles in flight
  stage(0); stage(1); stage(2);

  for (int kt = 0; kt < NKT - 3; ++kt) {
    asm volatile("s_waitcnt vmcnt(8)" ::: "memory");  // tile kt landed (everyone's, after barrier)
    __builtin_amdgcn_s_barrier();
    __builtin_amdgcn_sched_barrier(0);
    stage(kt + 3);            // overwrites buf[(kt-1)&3], safe: issued after barrier
    compute(kt);
  }
  asm volatile("s_waitcnt vmcnt(8)" ::: "memory");
  __builtin_amdgcn_s_barrier();
  __builtin_amdgcn_sched_barrier(0);
  compute(NKT - 3);
  asm volatile("s_waitcnt vmcnt(4)" ::: "memory");
  __builtin_amdgcn_s_barrier();
  __builtin_amdgcn_sched_barrier(0);
  compute(NKT - 2);
  asm volatile("s_waitcnt vmcnt(0)" ::: "memory");
  __builtin_amdgcn_s_barrier();
  __builtin_amdgcn_sched_barrier(0);
  compute(NKT - 1);

  // ---- dequant into fp32 ----
  const int orow0 = brow + wr * 128 + (lk << 2);
  const int ocol0 = bcol + wc * 64 + l16;
  float swv[4], bvv[4];
#pragma unroll
  for (int n = 0; n < 4; ++n) { swv[n] = sw[ocol0 + n * 16]; bvv[n] = bias[ocol0 + n * 16]; }

  f32x4 facc[8][4];
#pragma unroll
  for (int m = 0; m < 8; ++m)
#pragma unroll
    for (int r = 0; r < 4; ++r) {
      float sxv = sx[orow0 + m * 16 + r];
#pragma unroll
      for (int n = 0; n < 4; ++n) facc[m][n][r] = (float)acc[m][n][r] * sxv * swv[n];
    }

  // ---- outlier rank-64 addmm via f16 MFMA ----
  __syncthreads();
  // stage ox[256][64], ow[256][64] as f16, 128B rows, chunk ^= (row&7)
#pragma unroll
  for (int j = 0; j < 4; ++j) {
    int q = j * 512 + t;
    int row = q >> 3, cd = q & 7, cs = cd ^ (row & 7);
    const float* ga = ox + (size_t)(brow + row) * R_DIM + cs * 8;
    float4 f0 = *(const float4*)ga, f1 = *(const float4*)(ga + 4);
    f16x8 h;
    h[0] = (_Float16)f0.x; h[1] = (_Float16)f0.y; h[2] = (_Float16)f0.z; h[3] = (_Float16)f0.w;
    h[4] = (_Float16)f1.x; h[5] = (_Float16)f1.y; h[6] = (_Float16)f1.z; h[7] = (_Float16)f1.w;
    *(f16x8*)(smem + row * 128 + cd * 16) = h;
    const float* gb = ow + (size_t)(bcol + row) * R_DIM + cs * 8;
    f0 = *(const float4*)gb; f1 = *(const float4*)(gb + 4);
    f16x8 g;
    g[0] = (_Float16)f0.x; g[1] = (_Float16)f0.y; g[2] = (_Float16)f0.z; g[3] = (_Float16)f0.w;
    g[4] = (_Float16)f1.x; g[5] = (_Float16)f1.y; g[6] = (_Float16)f1.z; g[7] = (_Float16)f1.w;
    *(f16x8*)(smem + 32768 + row * 128 + cd * 16) = g;
  }
  __syncthreads();

  const char* qa = smem + (wr * 128 + l16) * 128;          // + m*2048
  const char* qb = smem + 32768 + (wc * 64 + l16) * 128;   // + n*2048
  const int x7 = l16 & 7;
#pragma unroll
  for (int s = 0; s < 2; ++s) {
    const int ca = ((s * 4 + lk) ^ x7) << 4;
    f16x8 hb[4];
#pragma unroll
    for (int n = 0; n < 4; ++n) hb[n] = *(const f16x8*)(qb + n * 2048 + ca);
#pragma unroll
    for (int m = 0; m < 8; ++m) {
      f16x8 ha = *(const f16x8*)(qa + m * 2048 + ca);
#pragma unroll
      for (int n = 0; n < 4; ++n)
        facc[m][n] = __builtin_amdgcn_mfma_f32_16x16x32_f16(ha, hb[n], facc[m][n], 0, 0, 0);
    }
  }

  // ---- store ----
#pragma unroll
  for (int m = 0; m < 8; ++m)
#pragma unroll
    for (int r = 0; r < 4; ++r) {
      float* po = out + (size_t)(orow0 + m * 16 + r) * OUT_DIM + ocol0;
#pragma unroll
      for (int n = 0; n < 4; ++n) po[n * 16] = facc[m][n][r] + bvv[n];
    }
}

// ---------------- fallback: 128x128, in-register pack (if ws too small) ----------------
__global__ __launch_bounds__(256)
void w4a4_gemm_fb(const int* __restrict__ A32, const int* __restrict__ B32,
                  const float* __restrict__ sx, const float* __restrict__ sw,
                  const float* __restrict__ ox, const float* __restrict__ ow,
                  const float* __restrict__ bias, float* __restrict__ out) {
  __shared__ __align__(16) unsigned char smem[32768];
  char* sA = (char*)smem;
  char* sB = (char*)smem + 8192;

  const int bid = blockIdx.x;
  const int swzb = (bid & 7) * 256 + (bid >> 3);
  const int tm = swzb >> 5, tn = swzb & 31;
  const int brow = tm * 128, bcol = tn * 128;

  const int t = threadIdx.x;
  const int w = t >> 6, l = t & 63;
  const int wr = w >> 1, wc = w & 1;
  const int l16 = l & 15, lk = l >> 4;
  (void)w;

  i32x4 iacc[4][4];
#pragma unroll
  for (int m = 0; m < 4; ++m)
#pragma unroll
    for (int n = 0; n < 4; ++n) iacc[m][n] = (i32x4){0, 0, 0, 0};

  const int ar = t >> 2;
  const int ac = (t & 3) << 4;
  const int* hA0 = A32 + (size_t)(brow + ar) * IN_DIM + ac;
  const int* hA1 = hA0 + (size_t)64 * IN_DIM;
  const int* hB0 = B32 + (size_t)(bcol + ar) * IN_DIM + ac;
  const int* hB1 = hB0 + (size_t)64 * IN_DIM;

  const char* fragA = sA + (size_t)(wr * 64 + l16) * 64 + lk * 16;
  const char* fragB = sB + (size_t)(wc * 64 + l16) * 64 + lk * 16;

  for (int k0 = 0; k0 < IN_DIM; k0 += 64) {
    const int4* pA0 = (const int4*)(hA0 + k0);
    int4 r0 = {pack4(pA0[0]), pack4(pA0[1]), pack4(pA0[2]), pack4(pA0[3])};
    *(int4*)(sA + t * 16) = r0;
    const int4* pA1 = (const int4*)(hA1 + k0);
    int4 r1 = {pack4(pA1[0]), pack4(pA1[1]), pack4(pA1[2]), pack4(pA1[3])};
    *(int4*)(sA + 4096 + t * 16) = r1;
    const int4* pB0 = (const int4*)(hB0 + k0);
    int4 r2 = {pack4(pB0[0]), pack4(pB0[1]), pack4(pB0[2]), pack4(pB0[3])};
    *(int4*)(sB + t * 16) = r2;
    const int4* pB1 = (const int4*)(hB1 + k0);
    int4 r3 = {pack4(pB1[0]), pack4(pB1[1]), pack4(pB1[2]), pack4(pB1[3])};
    *(int4*)(sB + 4096 + t * 16) = r3;
    __syncthreads();
    i32x4 av[4], bv[4];
#pragma unroll
    for (int m = 0; m < 4; ++m) av[m] = *(const i32x4*)(fragA + m * 1024);
#pragma unroll
    for (int n = 0; n < 4; ++n) bv[n] = *(const i32x4*)(fragB + n * 1024);
#pragma unroll
    for (int m = 0; m < 4; ++m)
#pragma unroll
      for (int n = 0; n < 4; ++n)
        iacc[m][n] = __builtin_amdgcn_mfma_i32_16x16x64_i8(av[m], bv[n], iacc[m][n], 0, 0, 0);
    __syncthreads();
  }

  const int orow = brow + wr * 64 + lk * 4;
  const int ocol = bcol + wc * 64 + l16;
  float swv[4], bvv[4];
#pragma unroll
  for (int n = 0; n < 4; ++n) { swv[n] = sw[ocol + n * 16]; bvv[n] = bias[ocol + n * 16]; }

  f32x4 facc[4][4];
#pragma unroll
  for (int m = 0; m < 4; ++m)
#pragma unroll
    for (int r = 0; r < 4; ++r) {
      float sxv = sx[orow + m * 16 + r];
#pragma unroll
      for (int n = 0; n < 4; ++n) facc[m][n][r] = (float)iacc[m][n][r] * sxv * swv[n];
    }

  _Float16* oA = (_Float16*)smem;
  _Float16* oB = (_Float16*)(smem + 16384);
#pragma unroll
  for (int j = 0; j < 4; ++j) {
    int c = j * 256 + t;
    int rr2 = c >> 3, c8 = (c & 7) << 3;
    const float* gp = ox + (size_t)(brow + rr2) * R_DIM + c8;
    float4 f0 = *(const float4*)gp;
    float4 f1 = *(const float4*)(gp + 4);
    f16x8 h;
    h[0] = (_Float16)f0.x; h[1] = (_Float16)f0.y; h[2] = (_Float16)f0.z; h[3] = (_Float16)f0.w;
    h[4] = (_Float16)f1.x; h[5] = (_Float16)f1.y; h[6] = (_Float16)f1.z; h[7] = (_Float16)f1.w;
    *(f16x8*)((char*)oA + (size_t)c * 16) = h;
    const float* gq = ow + (size_t)(bcol + rr2) * R_DIM + c8;
    f0 = *(const float4*)gq; f1 = *(const float4*)(gq + 4);
    f16x8 g;
    g[0] = (_Float16)f0.x; g[1] = (_Float16)f0.y; g[2] = (_Float16)f0.z; g[3] = (_Float16)f0.w;
    g[4] = (_Float16)f1.x; g[5] = (_Float16)f1.y; g[6] = (_Float16)f1.z; g[7] = (_Float16)f1.w;
    *(f16x8*)((char*)oB + (size_t)c * 16) = g;
  }
  __syncthreads();

  const char* qa = (const char*)oA + (size_t)(wr * 64 + l16) * 128 + lk * 16;
  const char* qb = (const char*)oB + (size_t)(wc * 64 + l16) * 128 + lk * 16;
#pragma unroll
  for (int s = 0; s < 2; ++s) {
    f16x8 ha[4], hb[4];
#pragma unroll
    for (int m = 0; m < 4; ++m) ha[m] = *(const f16x8*)(qa + m * 2048 + s * 64);
#pragma unroll
    for (int n = 0; n < 4; ++n) hb[n] = *(const f16x8*)(qb + n * 2048 + s * 64);
#pragma unroll
    for (int m = 0; m < 4; ++m)
#pragma unroll
      for (int n = 0; n < 4; ++n)
        facc[m][n] = __builtin_amdgcn_mfma_f32_16x16x32_f16(ha[m], hb[n], facc[m][n], 0, 0, 0);
  }

#pragma unroll
  for (int m = 0; m < 4; ++m)
#pragma unroll
    for (int r = 0; r < 4; ++r) {
      float* po = out + (size_t)(orow + m * 16 + r) * OUT_DIM + ocol;
#pragma unroll
      for (int n = 0; n < 4; ++n) po[n * 16] = facc[m][n][r] + bvv[n];
    }
}

extern "C" void kernel_launch(void* const* d_in, const int* in_sizes, int n_in,
                              void* d_out, int out_size, void* d_ws, size_t ws_size,
                              hipStream_t stream) {
  const int*   qx   = (const int*)d_in[0];
  const int*   wq   = (const int*)d_in[1];
  const float* sx   = (const float*)d_in[2];
  const float* sw   = (const float*)d_in[3];
  const float* ox   = (const float*)d_in[4];
  const float* ow   = (const float*)d_in[5];
  const float* bias = (const float*)d_in[6];
  float* out = (float*)d_out;

  const size_t needA = (size_t)T_DIM * IN_DIM;     // 32 MB
  const size_t needB = (size_t)OUT_DIM * IN_DIM;   // 16 MB

  if (ws_size >= needA + needB) {
    char* a8 = (char*)d_ws;
    char* b8 = a8 + needA;
    cvt_i8_kernel<<<1024, 256, 0, stream>>>((const int4*)qx, (int4*)a8, (int)(needA / 16));
    cvt_i8_kernel<<<1024, 256, 0, stream>>>((const int4*)wq, (int4*)b8, (int)(needB / 16));
    w4a4_gemm256<<<512, 512, 0, stream>>>(a8, b8, sx, sw, ox, ow, bias, out);
  } else {
    w4a4_gemm_fb<<<2048, 256, 0, stream>>>(qx, wq, sx, sw, ox, ow, bias, out);
  }
}